// Round 1
// baseline (525.542 us; speedup 1.0000x reference)
//
#include <hip/hip_runtime.h>
#include <hip/hip_bf16.h>
#include <hip/hip_fp16.h>

#define B_ 4
#define N_ 4096
#define F_ 128
#define NEG (-1e30f)

typedef _Float16 f16;
typedef _Float16 half8 __attribute__((ext_vector_type(8)));
typedef _Float16 half4 __attribute__((ext_vector_type(4)));
typedef float f32x4 __attribute__((ext_vector_type(4)));

// ---------------- k_wa: Wa[0:128) = W@a_src, Wa[128:256) = W@a_dst ----------
__global__ void k_wa(const float* __restrict__ W, const float* __restrict__ a_src,
                     const float* __restrict__ a_dst, float* __restrict__ Wa) {
    int f = threadIdx.x;  // 0..127
    float s0 = 0.f, s1 = 0.f;
    for (int o = 0; o < F_; ++o) {
        float w = W[f * F_ + o];
        s0 += w * a_src[o];
        s1 += w * a_dst[o];
    }
    Wa[f] = s0;
    Wa[F_ + f] = s1;
}

// ---------------- k_h: h = x@W (fp32), stored transposed as f16 ------------
// hT[b][c][i] = h[b][i][c], per-batch layout (128, 4096)
__global__ __launch_bounds__(256) void k_h(const float* __restrict__ x,
                                           const float* __restrict__ W,
                                           f16* __restrict__ hT) {
    __shared__ float xs[16][128];
    int t = threadIdx.x;
    long R0 = (long)blockIdx.x * 16;  // global row base over B*N
    const float4* xg = (const float4*)(x + R0 * 128);
    float4* xsv = (float4*)&xs[0][0];
    xsv[t] = xg[t];
    xsv[t + 256] = xg[t + 256];
    __syncthreads();
    int c = t & 127;
    int rg = t >> 7;  // 0 or 1 (uniform per wave -> xs broadcast)
    float acc[8] = {0, 0, 0, 0, 0, 0, 0, 0};
    for (int k = 0; k < 128; ++k) {
        float wv = W[k * 128 + c];  // coalesced, L2-resident
        #pragma unroll
        for (int q = 0; q < 8; ++q) acc[q] += xs[rg * 8 + q][k] * wv;
    }
    int b = (int)(R0 >> 12);
    int i = (int)(R0 & 4095);
    half8 hv;
    #pragma unroll
    for (int q = 0; q < 8; ++q) hv[q] = (f16)acc[q];
    *(half8*)(hT + ((long)(b * 128 + c) * 4096 + i + rg * 8)) = hv;
}

// ---------------- k_e: e_src/e_dst = x @ Wa --------------------------------
__global__ __launch_bounds__(256) void k_e(const float* __restrict__ x,
                                           const float* __restrict__ Wa,
                                           float* __restrict__ e_src,
                                           float* __restrict__ e_dst) {
    int t = threadIdx.x;
    int lane = t & 63;
    int w = t >> 6;
    long rg = (long)blockIdx.x * 4 + w;
    const float* xr = x + rg * 128;
    float x0 = xr[lane], x1 = xr[lane + 64];
    float s = x0 * Wa[lane] + x1 * Wa[lane + 64];
    float d = x0 * Wa[128 + lane] + x1 * Wa[192 + lane];
    #pragma unroll
    for (int off = 32; off; off >>= 1) {
        s += __shfl_xor(s, off, 64);
        d += __shfl_xor(d, off, 64);
    }
    if (lane == 0) { e_src[rg] = s; e_dst[rg] = d; }
}

// ---------------- k_attn: one block per (b,i) row --------------------------
__global__ __launch_bounds__(256) void k_attn(const int* __restrict__ adj,
                                              const float* __restrict__ e_src,
                                              const float* __restrict__ e_dst,
                                              float* __restrict__ attn) {
    int rg = blockIdx.x;  // 0..16383
    int b = rg >> 12;
    int i = rg & 4095;
    int t = threadIdx.x;
    float es = e_src[rg];
    const int* arow = adj + (long)i * N_;
    const float* ed = e_dst + b * N_;
    float p[16];
    float m = NEG;
    #pragma unroll
    for (int c = 0; c < 16; ++c) {
        int j = t + 256 * c;
        int a = arow[j];
        float e = es + ed[j];
        e = (e >= 0.f) ? e : 0.2f * e;  // leaky relu
        e = a ? e : NEG;                // mask
        p[c] = e;
        m = fmaxf(m, e);
    }
    #pragma unroll
    for (int off = 32; off; off >>= 1) m = fmaxf(m, __shfl_xor(m, off, 64));
    __shared__ float sred[8];
    int lane = t & 63, wid = t >> 6;
    if (lane == 0) sred[wid] = m;
    __syncthreads();
    m = fmaxf(fmaxf(sred[0], sred[1]), fmaxf(sred[2], sred[3]));
    float sum = 0.f;
    #pragma unroll
    for (int c = 0; c < 16; ++c) {
        float pv = __expf(p[c] - m);  // masked: exp(-1e30 - m) -> 0; all-masked: exp(0)=1 but inv=0
        p[c] = pv;
        sum += pv;
    }
    #pragma unroll
    for (int off = 32; off; off >>= 1) sum += __shfl_xor(sum, off, 64);
    if (lane == 0) sred[4 + wid] = sum;
    __syncthreads();
    sum = sred[4] + sred[5] + sred[6] + sred[7];
    float inv = (m <= -1e29f) ? 0.f : 1.f / sum;  // all-masked row -> zeros (nan_to_num)
    float* orow = attn + (long)rg * N_;
    #pragma unroll
    for (int c = 0; c < 16; ++c) orow[t + 256 * c] = p[c] * inv;
}

// ---------------- k_out: out = attn @ h via fp16 MFMA ----------------------
// Block: BM=32 rows x 128 cols, 4 waves (wave = 16 rows x 64 cols), K-step 32.
__global__ __launch_bounds__(256) void k_out(const float* __restrict__ attn,
                                             const f16* __restrict__ hT,
                                             float* __restrict__ out) {
    __shared__ __align__(16) f16 Alds[32][40];   // +8 pad: 80B rows -> 2-way (free) bank aliasing
    __shared__ __align__(16) f16 Blds[128][40];
    int t = threadIdx.x;
    int bx = blockIdx.x;
    int b = bx >> 7;             // 128 M-tiles per batch
    int i0 = (bx & 127) * 32;
    const float* Ab = attn + ((long)b * N_ + i0) * N_;
    const f16* Bb = hT + (long)b * 128 * 4096;

    int lane = t & 63, wid = t >> 6;
    int strip = (wid & 1) * 16;   // A-row strip of this wave
    int cb = (wid >> 1) * 64;     // col base of this wave
    int r16 = lane & 15;
    int kq = (lane >> 4) * 8;     // k offset within 32-wide step

    f32x4 acc[4] = {{0,0,0,0}, {0,0,0,0}, {0,0,0,0}, {0,0,0,0}};

    int ar = t >> 3;              // A staging: row 0..31
    int akc = (t & 7) * 4;        // 4 floats each
    int bc = t & 127;             // B staging: hT row (= out col)
    int bh = t >> 7;              // half of the 32 k's

    for (int kt = 0; kt < 128; ++kt) {
        int k0 = kt * 32;
        __syncthreads();
        // stage A: 32x32 fp32 -> f16  (8 lanes x 128B contiguous per row)
        float4 av = *(const float4*)(Ab + (long)ar * N_ + k0 + akc);
        half4 a4;
        a4[0] = (f16)av.x; a4[1] = (f16)av.y; a4[2] = (f16)av.z; a4[3] = (f16)av.w;
        *(half4*)&Alds[ar][akc] = a4;
        // stage B: hT tile [128][32] f16 (L2-resident)
        const f16* bsrc = Bb + (long)bc * 4096 + k0 + bh * 16;
        half8 b0 = *(const half8*)(bsrc);
        half8 b1 = *(const half8*)(bsrc + 8);
        *(half8*)&Blds[bc][bh * 16] = b0;
        *(half8*)&Blds[bc][bh * 16 + 8] = b1;
        __syncthreads();
        half8 af = *(const half8*)&Alds[strip + r16][kq];
        #pragma unroll
        for (int nt = 0; nt < 4; ++nt) {
            half8 bf = *(const half8*)&Blds[cb + nt * 16 + r16][kq];
            acc[nt] = __builtin_amdgcn_mfma_f32_16x16x32_f16(af, bf, acc[nt], 0, 0, 0);
        }
    }
    // epilogue: D row = strip + (lane>>4)*4 + reg, col = cb + nt*16 + r16
    int rbase = i0 + strip + (lane >> 4) * 4;
    float* ob = out + (long)b * N_ * 128;
    #pragma unroll
    for (int nt = 0; nt < 4; ++nt) {
        int col = cb + nt * 16 + r16;
        #pragma unroll
        for (int reg = 0; reg < 4; ++reg) {
            ob[(long)(rbase + reg) * 128 + col] = acc[nt][reg];
        }
    }
}

extern "C" void kernel_launch(void* const* d_in, const int* in_sizes, int n_in,
                              void* d_out, int out_size, void* d_ws, size_t ws_size,
                              hipStream_t stream) {
    const float* x     = (const float*)d_in[0];
    const int*   adj   = (const int*)d_in[1];
    const float* W     = (const float*)d_in[2];
    const float* a_src = (const float*)d_in[3];
    const float* a_dst = (const float*)d_in[4];
    float* out  = (float*)d_out;
    float* attn = out + (long)B_ * N_ * F_;  // outputs concatenated: out, then attn

    char* ws = (char*)d_ws;
    float* Wa    = (float*)(ws + 0);        // 256 f32
    float* e_src = (float*)(ws + 1024);     // 16384 f32
    float* e_dst = (float*)(ws + 66560);    // 16384 f32
    f16*   hT    = (f16*)(ws + 132096);     // 4*128*4096 f16 = 4 MB

    k_wa<<<dim3(1), dim3(128), 0, stream>>>(W, a_src, a_dst, Wa);
    k_h<<<dim3((B_ * N_) / 16), dim3(256), 0, stream>>>(x, W, hT);
    k_e<<<dim3((B_ * N_) / 4), dim3(256), 0, stream>>>(x, Wa, e_src, e_dst);
    k_attn<<<dim3(B_ * N_), dim3(256), 0, stream>>>(adj, e_src, e_dst, attn);
    k_out<<<dim3(B_ * (N_ / 32)), dim3(256), 0, stream>>>(attn, hT, out);
}